// Round 8
// baseline (444.677 us; speedup 1.0000x reference)
//
#include <hip/hip_runtime.h>
#include <stdint.h>

#define B_ 8
#define C_ 512
#define N_ 2048
#define H_ 8
#define D_ 64
#define HID_ 512

typedef short bf16x8 __attribute__((ext_vector_type(8)));
typedef float f32x4 __attribute__((ext_vector_type(4)));
typedef short short4v __attribute__((ext_vector_type(4)));

__device__ __forceinline__ float bf2f(unsigned short v) {
  union { float f; unsigned u; } c; c.u = ((unsigned)v) << 16; return c.f;
}
__device__ __forceinline__ unsigned short f2bf(float f) {
  union { float f; unsigned u; } c; c.f = f;
  unsigned u = c.u + 0x7FFFu + ((c.u >> 16) & 1u);
  return (unsigned short)(u >> 16);
}

// async global->LDS, 16B per lane. LDS dest is wave-uniform base + lane*16;
// the K-dim XOR swizzle is applied on the GLOBAL source address.
__device__ __forceinline__ void async_copy16(const void* g, void* l) {
  __builtin_amdgcn_global_load_lds((const __attribute__((address_space(1))) void*)g,
                                   (__attribute__((address_space(3))) void*)l,
                                   16, 0, 0);
}

// ---------------------------------------------------------------------------
// Kernel 0: f32 -> bf16 conversion for both weight matrices (one launch).
// ---------------------------------------------------------------------------
__global__ __launch_bounds__(256) void wcvt2(
    const float* __restrict__ s1, unsigned short* __restrict__ d1, int n1,
    const float* __restrict__ s2, unsigned short* __restrict__ d2, int n2) {
  int i = blockIdx.x * 256 + threadIdx.x;
  int stride = gridDim.x * 256;
  for (; i < n1 + n2; i += stride) {
    const float4 v = (i < n1) ? ((const float4*)s1)[i] : ((const float4*)s2)[i - n1];
    short4v p;
    p[0] = (short)f2bf(v.x); p[1] = (short)f2bf(v.y);
    p[2] = (short)f2bf(v.z); p[3] = (short)f2bf(v.w);
    if (i < n1) ((short4v*)d1)[i] = p; else ((short4v*)d2)[i - n1] = p;
  }
}

// ---------------------------------------------------------------------------
// Kernel 1: channel LayerNorm (over c=512) + transpose to xn_t[b][n][c] bf16.
// ---------------------------------------------------------------------------
__global__ __launch_bounds__(256) void ln_transpose(
    const float* __restrict__ x,            // (B, C, N) f32
    const float* __restrict__ g,            // (C,) f32
    unsigned short* __restrict__ xnt) {     // (B, N, C) bf16
  __shared__ float red[256], red2[256];
  __shared__ float meanS[64], rstdS[64];
  __shared__ __align__(16) unsigned short tile[64 * 65];

  const int b = blockIdx.y, n0 = blockIdx.x * 64;
  const int t = threadIdx.x;
  const int col = t & 63, q4 = t >> 6;
  const float* xb = x + (size_t)b * C_ * N_;

  float s = 0.f, s2 = 0.f;
  for (int c = q4 * 128; c < q4 * 128 + 128; ++c) {
    float v = xb[(size_t)c * N_ + n0 + col];
    s += v; s2 += v * v;
  }
  red[t] = s; red2[t] = s2;
  __syncthreads();
  if (t < 64) {
    float ts  = red[t]  + red[t + 64]  + red[t + 128]  + red[t + 192];
    float ts2 = red2[t] + red2[t + 64] + red2[t + 128] + red2[t + 192];
    float mean = ts * (1.0f / C_);
    float var  = ts2 * (1.0f / C_) - mean * mean;
    meanS[t] = mean;
    rstdS[t] = rsqrtf(var + 1e-5f);
  }

  unsigned short* xout = xnt + ((size_t)b * N_ + n0) * C_;
  for (int c0 = 0; c0 < C_; c0 += 64) {
    __syncthreads();
    for (int e = t; e < 64 * 64; e += 256) {
      int cl = e >> 6, nl = e & 63;
      int c = c0 + cl;
      float v = xb[(size_t)c * N_ + n0 + nl];
      tile[cl * 65 + nl] = f2bf((v - meanS[nl]) * rstdS[nl] * g[c]);
    }
    __syncthreads();
    for (int e = t; e < 64 * 64; e += 256) {
      int nl = e >> 6, cl = e & 63;
      xout[(size_t)nl * C_ + c0 + cl] = tile[cl * 65 + nl];
    }
  }
}

// ---------------------------------------------------------------------------
// Kernel 2: QKV GEMM (bf16, 128x128 tile, BK=64, K-chunk XOR swizzle).
// Epilogue: q -> (b,h,n,d)*0.125, k -> (b,h,n,d), v -> (b,h,d,n).
// ---------------------------------------------------------------------------
__global__ __launch_bounds__(256) void qkv_gemm(
    const unsigned short* __restrict__ W,    // (1536, 512) bf16
    const unsigned short* __restrict__ xnt,  // (B, N, C) bf16
    unsigned short* __restrict__ qt,
    unsigned short* __restrict__ kt,
    unsigned short* __restrict__ vt) {
  __shared__ __align__(16) short As[128 * 64];
  __shared__ __align__(16) short Bs[128 * 64];

  const int n0 = blockIdx.x * 128, m0 = blockIdx.y * 128, b = blockIdx.z;
  const int t = threadIdx.x;
  const int lane = t & 63, wave = t >> 6;
  const int col = lane & 15, quad = lane >> 4;
  const int wRow = (wave >> 1) * 64, wCol = (wave & 1) * 64;
  const unsigned short* xb = xnt + (size_t)b * N_ * C_;
  const int ldr = t >> 3;
  const int ldc8 = (((t & 7) ^ (ldr & 7)) * 8);
  const int cs = col & 7;

  f32x4 acc[4][4] = {};

  for (int k0 = 0; k0 < C_; k0 += 64) {
    __syncthreads();
#pragma unroll
    for (int call = 0; call < 4; ++call) {
      async_copy16(&W[(size_t)(m0 + call * 32 + ldr) * C_ + k0 + ldc8],
                   &As[call * 2048 + t * 8]);
      async_copy16(&xb[(size_t)(n0 + call * 32 + ldr) * C_ + k0 + ldc8],
                   &Bs[call * 2048 + t * 8]);
    }
    asm volatile("s_waitcnt vmcnt(0)" ::: "memory");
    __syncthreads();
#pragma unroll
    for (int ks = 0; ks < 2; ++ks) {
      bf16x8 a[4], bb[4];
      const int kc = ((ks * 4 + quad) ^ cs) * 8;
#pragma unroll
      for (int i = 0; i < 4; ++i)
        a[i] = *(const bf16x8*)&As[(wRow + i * 16 + col) * 64 + kc];
#pragma unroll
      for (int j = 0; j < 4; ++j)
        bb[j] = *(const bf16x8*)&Bs[(wCol + j * 16 + col) * 64 + kc];
#pragma unroll
      for (int i = 0; i < 4; ++i)
#pragma unroll
        for (int j = 0; j < 4; ++j)
          acc[i][j] = __builtin_amdgcn_mfma_f32_16x16x32_bf16(a[i], bb[j], acc[i][j], 0, 0, 0);
    }
  }

  const int sect = m0 >> 9;
  const int mloc = (m0 & 511) + wRow;
  const int h = mloc >> 6;
  if (sect < 2) {
    unsigned short* dst = (sect == 0 ? qt : kt) + ((size_t)b * H_ + h) * N_ * D_;
    const float scl = (sect == 0) ? 0.125f : 1.0f;
#pragma unroll
    for (int i = 0; i < 4; ++i) {
      int d0 = i * 16 + quad * 4;
#pragma unroll
      for (int j = 0; j < 4; ++j) {
        int n = n0 + wCol + j * 16 + col;
        short4v pk;
#pragma unroll
        for (int r = 0; r < 4; ++r) pk[r] = (short)f2bf(acc[i][j][r] * scl);
        *(short4v*)&dst[(size_t)n * D_ + d0] = pk;
      }
    }
  } else {
    unsigned short* dst = vt + ((size_t)b * H_ + h) * D_ * N_;
#pragma unroll
    for (int i = 0; i < 4; ++i) {
      int d0 = i * 16 + quad * 4;
#pragma unroll
      for (int j = 0; j < 4; ++j) {
        int n = n0 + wCol + j * 16 + col;
#pragma unroll
        for (int r = 0; r < 4; ++r)
          dst[(size_t)(d0 + r) * N_ + n] = f2bf(acc[i][j][r]);
      }
    }
  }
}

// ---------------------------------------------------------------------------
// Kernel 3: flash attention. BQ=256 per block, 4 waves x 64 Q-rows (K/V
// fragments reused across 4 i-tiles in registers). No-max softmax via __expf
// (R3-proven safe lowering: v_mul + v_exp with compiler hazard handling).
// P round-trips through wave-private LDS in 32-col quarters (PSTR4=40 ->
// Ps 20.5 KB, total LDS 52 KB -> 3 blocks/CU). l via MFMA with all-ones B.
// grid (8, 64).
// ---------------------------------------------------------------------------
#define PSTR4 40  // P quarter-buffer row stride (shorts)

__global__ __launch_bounds__(256, 3) void attn(
    const unsigned short* __restrict__ qt,   // (B,H,N,D), pre-scaled
    const unsigned short* __restrict__ kt,   // (B,H,N,D)
    const unsigned short* __restrict__ vt,   // (B,H,D,N)
    unsigned short* __restrict__ aot) {      // (B,N,HID)
  __shared__ __align__(16) short Ks[128 * 64];        // (j,d) swizzled; Q rows 0-127 at start
  __shared__ __align__(16) short Vs[64 * 128];        // (d,j) swizzled; Q rows 128-255 at start
  __shared__ __align__(16) short Ps[4 * 64 * PSTR4];  // per-wave P quarter (64 rows x 32 cols)

  const int q0 = blockIdx.x * 256;
  const int bh = blockIdx.y;
  const int t = threadIdx.x, lane = t & 63, wave = t >> 6;
  const int col = lane & 15, quad = lane >> 4;
  const int cs = col & 7;
  const unsigned short* qp = qt + (size_t)bh * N_ * D_;
  const unsigned short* kp = kt + (size_t)bh * N_ * D_;
  const unsigned short* vp = vt + (size_t)bh * D_ * N_;
  const int ldr = t >> 3;
  const int ldc8 = (((t & 7) ^ (ldr & 7)) * 8);
  const int vdr = t >> 4;
  const int vdc8 = (((t & 15) ^ (vdr & 7)) * 8);

  // stage Q tile (256x64, swizzled) into Ks+Vs, pull A-fragments to registers
#pragma unroll
  for (int call = 0; call < 4; ++call)
    async_copy16(&qp[(size_t)(q0 + call * 32 + ldr) * D_ + ldc8], &Ks[call * 2048 + t * 8]);
#pragma unroll
  for (int call = 0; call < 4; ++call)
    async_copy16(&qp[(size_t)(q0 + 128 + call * 32 + ldr) * D_ + ldc8], &Vs[call * 2048 + t * 8]);
  asm volatile("s_waitcnt vmcnt(0)" ::: "memory");
  __syncthreads();
  const short* Qsrc = (wave < 2) ? Ks : Vs;
  const int qr0 = (wave & 1) * 64;
  bf16x8 qf[4][2];
#pragma unroll
  for (int i = 0; i < 4; ++i)
#pragma unroll
    for (int ks = 0; ks < 2; ++ks)
      qf[i][ks] = *(const bf16x8*)&Qsrc[(qr0 + i * 16 + col) * 64 + ((ks * 4 + quad) ^ cs) * 8];
  __syncthreads();

  bf16x8 onesb;
#pragma unroll
  for (int j = 0; j < 8; ++j) onesb[j] = (short)0x3F80;  // bf16 1.0

  f32x4 O[4][4] = {};
  f32x4 L[4] = {};
  short* Pw = &Ps[wave * 64 * PSTR4];

  for (int j0 = 0; j0 < N_; j0 += 128) {
    __syncthreads();
#pragma unroll
    for (int call = 0; call < 4; ++call)
      async_copy16(&kp[(size_t)(j0 + call * 32 + ldr) * D_ + ldc8], &Ks[call * 2048 + t * 8]);
#pragma unroll
    for (int call = 0; call < 4; ++call)
      async_copy16(&vp[(size_t)(call * 16 + vdr) * N_ + j0 + vdc8], &Vs[call * 2048 + t * 8]);
    asm volatile("s_waitcnt vmcnt(0)" ::: "memory");
    __syncthreads();

    // four 32-col quarters: S -> exp(S) -> P(LDS) -> PV
#pragma unroll
    for (int qh = 0; qh < 4; ++qh) {
      f32x4 S[4][2] = {};
#pragma unroll
      for (int ks = 0; ks < 2; ++ks) {
        const int kc = ((ks * 4 + quad) ^ cs) * 8;
#pragma unroll
        for (int jtl = 0; jtl < 2; ++jtl) {
          bf16x8 kb = *(const bf16x8*)&Ks[((qh * 2 + jtl) * 16 + col) * 64 + kc];
#pragma unroll
          for (int i = 0; i < 4; ++i)
            S[i][jtl] = __builtin_amdgcn_mfma_f32_16x16x32_bf16(qf[i][ks], kb, S[i][jtl], 0, 0, 0);
        }
      }
      // P = exp(S) (no max subtraction: |S| small, f32-safe); round to bf16
#pragma unroll
      for (int i = 0; i < 4; ++i)
#pragma unroll
        for (int jtl = 0; jtl < 2; ++jtl)
#pragma unroll
          for (int r = 0; r < 4; ++r) {
            float p = __expf(S[i][jtl][r]);
            unsigned u;
            __builtin_memcpy(&u, &p, 4);
            Pw[(i * 16 + quad * 4 + r) * PSTR4 + jtl * 16 + col] =
                (unsigned short)((u + 0x8000u) >> 16);
          }
      // PV on this quarter (DS ops in-order per wave: no barrier needed)
      bf16x8 pa[4], vb[4];
#pragma unroll
      for (int i = 0; i < 4; ++i)
        pa[i] = *(const bf16x8*)&Pw[(i * 16 + col) * PSTR4 + quad * 8];
      const int vc = ((qh * 4 + quad) ^ cs) * 8;
#pragma unroll
      for (int dt = 0; dt < 4; ++dt)
        vb[dt] = *(const bf16x8*)&Vs[(dt * 16 + col) * 128 + vc];
#pragma unroll
      for (int i = 0; i < 4; ++i) {
#pragma unroll
        for (int dt = 0; dt < 4; ++dt)
          O[i][dt] = __builtin_amdgcn_mfma_f32_16x16x32_bf16(pa[i], vb[dt], O[i][dt], 0, 0, 0);
        L[i] = __builtin_amdgcn_mfma_f32_16x16x32_bf16(pa[i], onesb, L[i], 0, 0, 0);
      }
    }
  }

  // epilogue: normalize by l, write ao_t[b][n][h*64+d]
  const int b = bh >> 3, h = bh & 7;
  unsigned short* ob = aot + (size_t)b * N_ * HID_;
#pragma unroll
  for (int i = 0; i < 4; ++i) {
#pragma unroll
    for (int r = 0; r < 4; ++r) {
      int n = q0 + wave * 64 + i * 16 + quad * 4 + r;
      float inv = 1.0f / L[i][r];
#pragma unroll
      for (int dt = 0; dt < 4; ++dt)
        ob[(size_t)n * HID_ + h * 64 + dt * 16 + col] = f2bf(O[i][dt][r] * inv);
    }
  }
}

// ---------------------------------------------------------------------------
// Kernel 4: out GEMM (bf16 MFMA, f32 bias, f32 output), K-chunk XOR swizzle.
// ---------------------------------------------------------------------------
__global__ __launch_bounds__(256) void out_gemm(
    const unsigned short* __restrict__ W,    // (512, 512) bf16
    const unsigned short* __restrict__ aot,  // (B, N, HID) bf16
    const float* __restrict__ bias,          // (512,) f32
    float* __restrict__ out) {               // (B, C, N) f32
  __shared__ __align__(16) short As[128 * 64];
  __shared__ __align__(16) short Bs[128 * 64];

  const int n0 = blockIdx.x * 128, m0 = blockIdx.y * 128, b = blockIdx.z;
  const int t = threadIdx.x;
  const int lane = t & 63, wave = t >> 6;
  const int col = lane & 15, quad = lane >> 4;
  const int wRow = (wave >> 1) * 64, wCol = (wave & 1) * 64;
  const unsigned short* xb = aot + (size_t)b * N_ * HID_;
  const int ldr = t >> 3;
  const int ldc8 = (((t & 7) ^ (ldr & 7)) * 8);
  const int cs = col & 7;

  f32x4 acc[4][4] = {};

  for (int k0 = 0; k0 < HID_; k0 += 64) {
    __syncthreads();
#pragma unroll
    for (int call = 0; call < 4; ++call) {
      async_copy16(&W[(size_t)(m0 + call * 32 + ldr) * HID_ + k0 + ldc8],
                   &As[call * 2048 + t * 8]);
      async_copy16(&xb[(size_t)(n0 + call * 32 + ldr) * HID_ + k0 + ldc8],
                   &Bs[call * 2048 + t * 8]);
    }
    asm volatile("s_waitcnt vmcnt(0)" ::: "memory");
    __syncthreads();
#pragma unroll
    for (int ks = 0; ks < 2; ++ks) {
      bf16x8 a[4], bb[4];
      const int kc = ((ks * 4 + quad) ^ cs) * 8;
#pragma unroll
      for (int i = 0; i < 4; ++i)
        a[i] = *(const bf16x8*)&As[(wRow + i * 16 + col) * 64 + kc];
#pragma unroll
      for (int j = 0; j < 4; ++j)
        bb[j] = *(const bf16x8*)&Bs[(wCol + j * 16 + col) * 64 + kc];
#pragma unroll
      for (int i = 0; i < 4; ++i)
#pragma unroll
        for (int j = 0; j < 4; ++j)
          acc[i][j] = __builtin_amdgcn_mfma_f32_16x16x32_bf16(a[i], bb[j], acc[i][j], 0, 0, 0);
    }
  }

#pragma unroll
  for (int i = 0; i < 4; ++i) {
#pragma unroll
    for (int r = 0; r < 4; ++r) {
      int m = m0 + wRow + i * 16 + quad * 4 + r;
      float bv = bias[m];
#pragma unroll
      for (int j = 0; j < 4; ++j) {
        int n = n0 + wCol + j * 16 + col;
        out[((size_t)b * C_ + m) * N_ + n] = acc[i][j][r] + bv;
      }
    }
  }
}

extern "C" void kernel_launch(void* const* d_in, const int* in_sizes, int n_in,
                              void* d_out, int out_size, void* d_ws, size_t ws_size,
                              hipStream_t stream) {
  const float* x    = (const float*)d_in[0];
  const float* g    = (const float*)d_in[1];
  const float* Wqkv = (const float*)d_in[2];
  const float* Wout = (const float*)d_in[3];
  const float* bout = (const float*)d_in[4];
  float* out = (float*)d_out;

  unsigned short* ws  = (unsigned short*)d_ws;
  unsigned short* xnt = ws;                                  // B*N*C
  unsigned short* qt  = xnt + (size_t)B_ * N_ * C_;
  unsigned short* kt  = qt  + (size_t)B_ * H_ * N_ * D_;
  unsigned short* vt  = kt  + (size_t)B_ * H_ * N_ * D_;
  unsigned short* aot = vt  + (size_t)B_ * H_ * D_ * N_;     // B*N*HID
  unsigned short* Wqb = aot + (size_t)B_ * N_ * HID_;        // 1536*512
  unsigned short* Wob = Wqb + (size_t)3 * HID_ * C_;         // 512*512

  wcvt2<<<dim3(256), 256, 0, stream>>>(Wqkv, Wqb, 3 * HID_ * C_ / 4,
                                       Wout, Wob, C_ * HID_ / 4);
  ln_transpose<<<dim3(N_ / 64, B_), 256, 0, stream>>>(x, g, xnt);
  qkv_gemm<<<dim3(N_ / 128, 12, B_), 256, 0, stream>>>(Wqb, xnt, qt, kt, vt);
  attn<<<dim3(N_ / 256, B_ * H_), 256, 0, stream>>>(qt, kt, vt, aot);
  out_gemm<<<dim3(N_ / 128, 4, B_), 256, 0, stream>>>(Wob, aot, bout, out);
}

// Round 9
// 292.895 us; speedup vs baseline: 1.5182x; 1.5182x over previous
//
#include <hip/hip_runtime.h>
#include <stdint.h>

#define B_ 8
#define C_ 512
#define N_ 2048
#define H_ 8
#define D_ 64
#define HID_ 512

typedef short bf16x8 __attribute__((ext_vector_type(8)));
typedef float f32x4 __attribute__((ext_vector_type(4)));
typedef short short4v __attribute__((ext_vector_type(4)));

__device__ __forceinline__ float bf2f(unsigned short v) {
  union { float f; unsigned u; } c; c.u = ((unsigned)v) << 16; return c.f;
}
__device__ __forceinline__ unsigned short f2bf(float f) {
  union { float f; unsigned u; } c; c.f = f;
  unsigned u = c.u + 0x7FFFu + ((c.u >> 16) & 1u);
  return (unsigned short)(u >> 16);
}

// async global->LDS, 16B per lane. LDS dest is wave-uniform base + lane*16;
// the K-dim XOR swizzle is applied on the GLOBAL source address.
__device__ __forceinline__ void async_copy16(const void* g, void* l) {
  __builtin_amdgcn_global_load_lds((const __attribute__((address_space(1))) void*)g,
                                   (__attribute__((address_space(3))) void*)l,
                                   16, 0, 0);
}

// ---------------------------------------------------------------------------
// Kernel 0: f32 -> bf16 conversion for both weight matrices (one launch).
// ---------------------------------------------------------------------------
__global__ __launch_bounds__(256) void wcvt2(
    const float* __restrict__ s1, unsigned short* __restrict__ d1, int n1,
    const float* __restrict__ s2, unsigned short* __restrict__ d2, int n2) {
  int i = blockIdx.x * 256 + threadIdx.x;
  int stride = gridDim.x * 256;
  for (; i < n1 + n2; i += stride) {
    const float4 v = (i < n1) ? ((const float4*)s1)[i] : ((const float4*)s2)[i - n1];
    short4v p;
    p[0] = (short)f2bf(v.x); p[1] = (short)f2bf(v.y);
    p[2] = (short)f2bf(v.z); p[3] = (short)f2bf(v.w);
    if (i < n1) ((short4v*)d1)[i] = p; else ((short4v*)d2)[i - n1] = p;
  }
}

// ---------------------------------------------------------------------------
// Kernel 1: channel LayerNorm (over c=512) + transpose to xn_t[b][n][c] bf16.
// ---------------------------------------------------------------------------
__global__ __launch_bounds__(256) void ln_transpose(
    const float* __restrict__ x,            // (B, C, N) f32
    const float* __restrict__ g,            // (C,) f32
    unsigned short* __restrict__ xnt) {     // (B, N, C) bf16
  __shared__ float red[256], red2[256];
  __shared__ float meanS[64], rstdS[64];
  __shared__ __align__(16) unsigned short tile[64 * 65];

  const int b = blockIdx.y, n0 = blockIdx.x * 64;
  const int t = threadIdx.x;
  const int col = t & 63, q4 = t >> 6;
  const float* xb = x + (size_t)b * C_ * N_;

  float s = 0.f, s2 = 0.f;
  for (int c = q4 * 128; c < q4 * 128 + 128; ++c) {
    float v = xb[(size_t)c * N_ + n0 + col];
    s += v; s2 += v * v;
  }
  red[t] = s; red2[t] = s2;
  __syncthreads();
  if (t < 64) {
    float ts  = red[t]  + red[t + 64]  + red[t + 128]  + red[t + 192];
    float ts2 = red2[t] + red2[t + 64] + red2[t + 128] + red2[t + 192];
    float mean = ts * (1.0f / C_);
    float var  = ts2 * (1.0f / C_) - mean * mean;
    meanS[t] = mean;
    rstdS[t] = rsqrtf(var + 1e-5f);
  }

  unsigned short* xout = xnt + ((size_t)b * N_ + n0) * C_;
  for (int c0 = 0; c0 < C_; c0 += 64) {
    __syncthreads();
    for (int e = t; e < 64 * 64; e += 256) {
      int cl = e >> 6, nl = e & 63;
      int c = c0 + cl;
      float v = xb[(size_t)c * N_ + n0 + nl];
      tile[cl * 65 + nl] = f2bf((v - meanS[nl]) * rstdS[nl] * g[c]);
    }
    __syncthreads();
    for (int e = t; e < 64 * 64; e += 256) {
      int nl = e >> 6, cl = e & 63;
      xout[(size_t)nl * C_ + c0 + cl] = tile[cl * 65 + nl];
    }
  }
}

// ---------------------------------------------------------------------------
// Kernel 2: QKV GEMM (bf16, 128x128 tile, BK=64, K-chunk XOR swizzle).
// Epilogue: q -> (b,h,n,d)*0.125, k -> (b,h,n,d), v -> (b,h,d,n).
// ---------------------------------------------------------------------------
__global__ __launch_bounds__(256) void qkv_gemm(
    const unsigned short* __restrict__ W,    // (1536, 512) bf16
    const unsigned short* __restrict__ xnt,  // (B, N, C) bf16
    unsigned short* __restrict__ qt,
    unsigned short* __restrict__ kt,
    unsigned short* __restrict__ vt) {
  __shared__ __align__(16) short As[128 * 64];
  __shared__ __align__(16) short Bs[128 * 64];

  const int n0 = blockIdx.x * 128, m0 = blockIdx.y * 128, b = blockIdx.z;
  const int t = threadIdx.x;
  const int lane = t & 63, wave = t >> 6;
  const int col = lane & 15, quad = lane >> 4;
  const int wRow = (wave >> 1) * 64, wCol = (wave & 1) * 64;
  const unsigned short* xb = xnt + (size_t)b * N_ * C_;
  const int ldr = t >> 3;
  const int ldc8 = (((t & 7) ^ (ldr & 7)) * 8);
  const int cs = col & 7;

  f32x4 acc[4][4] = {};

  for (int k0 = 0; k0 < C_; k0 += 64) {
    __syncthreads();
#pragma unroll
    for (int call = 0; call < 4; ++call) {
      async_copy16(&W[(size_t)(m0 + call * 32 + ldr) * C_ + k0 + ldc8],
                   &As[call * 2048 + t * 8]);
      async_copy16(&xb[(size_t)(n0 + call * 32 + ldr) * C_ + k0 + ldc8],
                   &Bs[call * 2048 + t * 8]);
    }
    asm volatile("s_waitcnt vmcnt(0)" ::: "memory");
    __syncthreads();
#pragma unroll
    for (int ks = 0; ks < 2; ++ks) {
      bf16x8 a[4], bb[4];
      const int kc = ((ks * 4 + quad) ^ cs) * 8;
#pragma unroll
      for (int i = 0; i < 4; ++i)
        a[i] = *(const bf16x8*)&As[(wRow + i * 16 + col) * 64 + kc];
#pragma unroll
      for (int j = 0; j < 4; ++j)
        bb[j] = *(const bf16x8*)&Bs[(wCol + j * 16 + col) * 64 + kc];
#pragma unroll
      for (int i = 0; i < 4; ++i)
#pragma unroll
        for (int j = 0; j < 4; ++j)
          acc[i][j] = __builtin_amdgcn_mfma_f32_16x16x32_bf16(a[i], bb[j], acc[i][j], 0, 0, 0);
    }
  }

  const int sect = m0 >> 9;
  const int mloc = (m0 & 511) + wRow;
  const int h = mloc >> 6;
  if (sect < 2) {
    unsigned short* dst = (sect == 0 ? qt : kt) + ((size_t)b * H_ + h) * N_ * D_;
    const float scl = (sect == 0) ? 0.125f : 1.0f;
#pragma unroll
    for (int i = 0; i < 4; ++i) {
      int d0 = i * 16 + quad * 4;
#pragma unroll
      for (int j = 0; j < 4; ++j) {
        int n = n0 + wCol + j * 16 + col;
        short4v pk;
#pragma unroll
        for (int r = 0; r < 4; ++r) pk[r] = (short)f2bf(acc[i][j][r] * scl);
        *(short4v*)&dst[(size_t)n * D_ + d0] = pk;
      }
    }
  } else {
    unsigned short* dst = vt + ((size_t)b * H_ + h) * D_ * N_;
#pragma unroll
    for (int i = 0; i < 4; ++i) {
      int d0 = i * 16 + quad * 4;
#pragma unroll
      for (int j = 0; j < 4; ++j) {
        int n = n0 + wCol + j * 16 + col;
#pragma unroll
        for (int r = 0; r < 4; ++r)
          dst[(size_t)(d0 + r) * N_ + n] = f2bf(acc[i][j][r]);
      }
    }
  }
}

// ---------------------------------------------------------------------------
// Kernel 3: flash attention. BQ=256 per block, 4 waves x 64 Q-rows (K/V
// fragments reused across 4 i-tiles in registers). No-max softmax via __expf.
// P round-trips through wave-private LDS in 32-col quarters (PSTR4=40 ->
// Ps 20.5 KB, total LDS 52 KB -> 3 blocks/CU if VGPR <= 170).
// __launch_bounds__(256, 2): the (256,3) cap of ~170 VGPRs forced accumulator
// spills (R8: 640 MB scratch traffic, attn 257 us). (256,2) => no spill
// (R4-proven, 120 VGPRs); occupancy then LDS-limited at 3 blocks/CU.
// l via MFMA with all-ones B. grid (8, 64).
// ---------------------------------------------------------------------------
#define PSTR4 40  // P quarter-buffer row stride (shorts)

__global__ __launch_bounds__(256, 2) void attn(
    const unsigned short* __restrict__ qt,   // (B,H,N,D), pre-scaled
    const unsigned short* __restrict__ kt,   // (B,H,N,D)
    const unsigned short* __restrict__ vt,   // (B,H,D,N)
    unsigned short* __restrict__ aot) {      // (B,N,HID)
  __shared__ __align__(16) short Ks[128 * 64];        // (j,d) swizzled; Q rows 0-127 at start
  __shared__ __align__(16) short Vs[64 * 128];        // (d,j) swizzled; Q rows 128-255 at start
  __shared__ __align__(16) short Ps[4 * 64 * PSTR4];  // per-wave P quarter (64 rows x 32 cols)

  const int q0 = blockIdx.x * 256;
  const int bh = blockIdx.y;
  const int t = threadIdx.x, lane = t & 63, wave = t >> 6;
  const int col = lane & 15, quad = lane >> 4;
  const int cs = col & 7;
  const unsigned short* qp = qt + (size_t)bh * N_ * D_;
  const unsigned short* kp = kt + (size_t)bh * N_ * D_;
  const unsigned short* vp = vt + (size_t)bh * D_ * N_;
  const int ldr = t >> 3;
  const int ldc8 = (((t & 7) ^ (ldr & 7)) * 8);
  const int vdr = t >> 4;
  const int vdc8 = (((t & 15) ^ (vdr & 7)) * 8);

  // stage Q tile (256x64, swizzled) into Ks+Vs, pull A-fragments to registers
#pragma unroll
  for (int call = 0; call < 4; ++call)
    async_copy16(&qp[(size_t)(q0 + call * 32 + ldr) * D_ + ldc8], &Ks[call * 2048 + t * 8]);
#pragma unroll
  for (int call = 0; call < 4; ++call)
    async_copy16(&qp[(size_t)(q0 + 128 + call * 32 + ldr) * D_ + ldc8], &Vs[call * 2048 + t * 8]);
  asm volatile("s_waitcnt vmcnt(0)" ::: "memory");
  __syncthreads();
  const short* Qsrc = (wave < 2) ? Ks : Vs;
  const int qr0 = (wave & 1) * 64;
  bf16x8 qf[4][2];
#pragma unroll
  for (int i = 0; i < 4; ++i)
#pragma unroll
    for (int ks = 0; ks < 2; ++ks)
      qf[i][ks] = *(const bf16x8*)&Qsrc[(qr0 + i * 16 + col) * 64 + ((ks * 4 + quad) ^ cs) * 8];
  __syncthreads();

  bf16x8 onesb;
#pragma unroll
  for (int j = 0; j < 8; ++j) onesb[j] = (short)0x3F80;  // bf16 1.0

  f32x4 O[4][4] = {};
  f32x4 L[4] = {};
  short* Pw = &Ps[wave * 64 * PSTR4];

  for (int j0 = 0; j0 < N_; j0 += 128) {
    __syncthreads();
#pragma unroll
    for (int call = 0; call < 4; ++call)
      async_copy16(&kp[(size_t)(j0 + call * 32 + ldr) * D_ + ldc8], &Ks[call * 2048 + t * 8]);
#pragma unroll
    for (int call = 0; call < 4; ++call)
      async_copy16(&vp[(size_t)(call * 16 + vdr) * N_ + j0 + vdc8], &Vs[call * 2048 + t * 8]);
    asm volatile("s_waitcnt vmcnt(0)" ::: "memory");
    __syncthreads();

    // four 32-col quarters: S -> exp(S) -> P(LDS) -> PV
#pragma unroll
    for (int qh = 0; qh < 4; ++qh) {
      f32x4 S[4][2] = {};
#pragma unroll
      for (int ks = 0; ks < 2; ++ks) {
        const int kc = ((ks * 4 + quad) ^ cs) * 8;
#pragma unroll
        for (int jtl = 0; jtl < 2; ++jtl) {
          bf16x8 kb = *(const bf16x8*)&Ks[((qh * 2 + jtl) * 16 + col) * 64 + kc];
#pragma unroll
          for (int i = 0; i < 4; ++i)
            S[i][jtl] = __builtin_amdgcn_mfma_f32_16x16x32_bf16(qf[i][ks], kb, S[i][jtl], 0, 0, 0);
        }
      }
      // P = exp(S) (no max subtraction: |S| small, f32-safe); round to bf16
#pragma unroll
      for (int i = 0; i < 4; ++i)
#pragma unroll
        for (int jtl = 0; jtl < 2; ++jtl)
#pragma unroll
          for (int r = 0; r < 4; ++r) {
            float p = __expf(S[i][jtl][r]);
            unsigned u;
            __builtin_memcpy(&u, &p, 4);
            Pw[(i * 16 + quad * 4 + r) * PSTR4 + jtl * 16 + col] =
                (unsigned short)((u + 0x8000u) >> 16);
          }
      // PV on this quarter (DS ops in-order per wave: no barrier needed)
      bf16x8 pa[4], vb[4];
#pragma unroll
      for (int i = 0; i < 4; ++i)
        pa[i] = *(const bf16x8*)&Pw[(i * 16 + col) * PSTR4 + quad * 8];
      const int vc = ((qh * 4 + quad) ^ cs) * 8;
#pragma unroll
      for (int dt = 0; dt < 4; ++dt)
        vb[dt] = *(const bf16x8*)&Vs[(dt * 16 + col) * 128 + vc];
#pragma unroll
      for (int i = 0; i < 4; ++i) {
#pragma unroll
        for (int dt = 0; dt < 4; ++dt)
          O[i][dt] = __builtin_amdgcn_mfma_f32_16x16x32_bf16(pa[i], vb[dt], O[i][dt], 0, 0, 0);
        L[i] = __builtin_amdgcn_mfma_f32_16x16x32_bf16(pa[i], onesb, L[i], 0, 0, 0);
      }
    }
  }

  // epilogue: normalize by l, write ao_t[b][n][h*64+d]
  const int b = bh >> 3, h = bh & 7;
  unsigned short* ob = aot + (size_t)b * N_ * HID_;
#pragma unroll
  for (int i = 0; i < 4; ++i) {
#pragma unroll
    for (int r = 0; r < 4; ++r) {
      int n = q0 + wave * 64 + i * 16 + quad * 4 + r;
      float inv = 1.0f / L[i][r];
#pragma unroll
      for (int dt = 0; dt < 4; ++dt)
        ob[(size_t)n * HID_ + h * 64 + dt * 16 + col] = f2bf(O[i][dt][r] * inv);
    }
  }
}

// ---------------------------------------------------------------------------
// Kernel 4: out GEMM (bf16 MFMA, f32 bias, f32 output), K-chunk XOR swizzle.
// ---------------------------------------------------------------------------
__global__ __launch_bounds__(256) void out_gemm(
    const unsigned short* __restrict__ W,    // (512, 512) bf16
    const unsigned short* __restrict__ aot,  // (B, N, HID) bf16
    const float* __restrict__ bias,          // (512,) f32
    float* __restrict__ out) {               // (B, C, N) f32
  __shared__ __align__(16) short As[128 * 64];
  __shared__ __align__(16) short Bs[128 * 64];

  const int n0 = blockIdx.x * 128, m0 = blockIdx.y * 128, b = blockIdx.z;
  const int t = threadIdx.x;
  const int lane = t & 63, wave = t >> 6;
  const int col = lane & 15, quad = lane >> 4;
  const int wRow = (wave >> 1) * 64, wCol = (wave & 1) * 64;
  const unsigned short* xb = aot + (size_t)b * N_ * HID_;
  const int ldr = t >> 3;
  const int ldc8 = (((t & 7) ^ (ldr & 7)) * 8);
  const int cs = col & 7;

  f32x4 acc[4][4] = {};

  for (int k0 = 0; k0 < HID_; k0 += 64) {
    __syncthreads();
#pragma unroll
    for (int call = 0; call < 4; ++call) {
      async_copy16(&W[(size_t)(m0 + call * 32 + ldr) * HID_ + k0 + ldc8],
                   &As[call * 2048 + t * 8]);
      async_copy16(&xb[(size_t)(n0 + call * 32 + ldr) * HID_ + k0 + ldc8],
                   &Bs[call * 2048 + t * 8]);
    }
    asm volatile("s_waitcnt vmcnt(0)" ::: "memory");
    __syncthreads();
#pragma unroll
    for (int ks = 0; ks < 2; ++ks) {
      bf16x8 a[4], bb[4];
      const int kc = ((ks * 4 + quad) ^ cs) * 8;
#pragma unroll
      for (int i = 0; i < 4; ++i)
        a[i] = *(const bf16x8*)&As[(wRow + i * 16 + col) * 64 + kc];
#pragma unroll
      for (int j = 0; j < 4; ++j)
        bb[j] = *(const bf16x8*)&Bs[(wCol + j * 16 + col) * 64 + kc];
#pragma unroll
      for (int i = 0; i < 4; ++i)
#pragma unroll
        for (int j = 0; j < 4; ++j)
          acc[i][j] = __builtin_amdgcn_mfma_f32_16x16x32_bf16(a[i], bb[j], acc[i][j], 0, 0, 0);
    }
  }

#pragma unroll
  for (int i = 0; i < 4; ++i) {
#pragma unroll
    for (int r = 0; r < 4; ++r) {
      int m = m0 + wRow + i * 16 + quad * 4 + r;
      float bv = bias[m];
#pragma unroll
      for (int j = 0; j < 4; ++j) {
        int n = n0 + wCol + j * 16 + col;
        out[((size_t)b * C_ + m) * N_ + n] = acc[i][j][r] + bv;
      }
    }
  }
}

extern "C" void kernel_launch(void* const* d_in, const int* in_sizes, int n_in,
                              void* d_out, int out_size, void* d_ws, size_t ws_size,
                              hipStream_t stream) {
  const float* x    = (const float*)d_in[0];
  const float* g    = (const float*)d_in[1];
  const float* Wqkv = (const float*)d_in[2];
  const float* Wout = (const float*)d_in[3];
  const float* bout = (const float*)d_in[4];
  float* out = (float*)d_out;

  unsigned short* ws  = (unsigned short*)d_ws;
  unsigned short* xnt = ws;                                  // B*N*C
  unsigned short* qt  = xnt + (size_t)B_ * N_ * C_;
  unsigned short* kt  = qt  + (size_t)B_ * H_ * N_ * D_;
  unsigned short* vt  = kt  + (size_t)B_ * H_ * N_ * D_;
  unsigned short* aot = vt  + (size_t)B_ * H_ * D_ * N_;     // B*N*HID
  unsigned short* Wqb = aot + (size_t)B_ * N_ * HID_;        // 1536*512
  unsigned short* Wob = Wqb + (size_t)3 * HID_ * C_;         // 512*512

  wcvt2<<<dim3(256), 256, 0, stream>>>(Wqkv, Wqb, 3 * HID_ * C_ / 4,
                                       Wout, Wob, C_ * HID_ / 4);
  ln_transpose<<<dim3(N_ / 64, B_), 256, 0, stream>>>(x, g, xnt);
  qkv_gemm<<<dim3(N_ / 128, 12, B_), 256, 0, stream>>>(Wqb, xnt, qt, kt, vt);
  attn<<<dim3(N_ / 256, B_ * H_), 256, 0, stream>>>(qt, kt, vt, aot);
  out_gemm<<<dim3(N_ / 128, 4, B_), 256, 0, stream>>>(Wob, aot, bout, out);
}

// Round 10
// 247.386 us; speedup vs baseline: 1.7975x; 1.1840x over previous
//
#include <hip/hip_runtime.h>
#include <stdint.h>

#define B_ 8
#define C_ 512
#define N_ 2048
#define H_ 8
#define D_ 64
#define HID_ 512

typedef short bf16x8 __attribute__((ext_vector_type(8)));
typedef float f32x4 __attribute__((ext_vector_type(4)));
typedef short short4v __attribute__((ext_vector_type(4)));

__device__ __forceinline__ float bf2f(unsigned short v) {
  union { float f; unsigned u; } c; c.u = ((unsigned)v) << 16; return c.f;
}
__device__ __forceinline__ unsigned short f2bf(float f) {
  union { float f; unsigned u; } c; c.f = f;
  unsigned u = c.u + 0x7FFFu + ((c.u >> 16) & 1u);
  return (unsigned short)(u >> 16);
}

// async global->LDS, 16B per lane. LDS dest is wave-uniform base + lane*16;
// any swizzle must be applied on the GLOBAL source address.
__device__ __forceinline__ void async_copy16(const void* g, void* l) {
  __builtin_amdgcn_global_load_lds((const __attribute__((address_space(1))) void*)g,
                                   (__attribute__((address_space(3))) void*)l,
                                   16, 0, 0);
}

// ---------------------------------------------------------------------------
// Kernel 0: f32 -> bf16 conversion for both weight matrices (one launch).
// ---------------------------------------------------------------------------
__global__ __launch_bounds__(256) void wcvt2(
    const float* __restrict__ s1, unsigned short* __restrict__ d1, int n1,
    const float* __restrict__ s2, unsigned short* __restrict__ d2, int n2) {
  int i = blockIdx.x * 256 + threadIdx.x;
  int stride = gridDim.x * 256;
  for (; i < n1 + n2; i += stride) {
    const float4 v = (i < n1) ? ((const float4*)s1)[i] : ((const float4*)s2)[i - n1];
    short4v p;
    p[0] = (short)f2bf(v.x); p[1] = (short)f2bf(v.y);
    p[2] = (short)f2bf(v.z); p[3] = (short)f2bf(v.w);
    if (i < n1) ((short4v*)d1)[i] = p; else ((short4v*)d2)[i - n1] = p;
  }
}

// ---------------------------------------------------------------------------
// Kernel 1: channel LayerNorm + transpose, SINGLE global read of x.
// Full 512c x 64n f32 slab staged in LDS via global_load_lds (128 KB, the
// required linear [c][n] layout is 2-way-conflict-free for both the stats
// read and the normalize read since lanes vary n). Stats from LDS; normalize
// through a padded 64x65 bf16 tile; coalesced short4 writes.
// grid (32, 8) = 256 blocks = 1 block/CU (LDS ~138 KB).
// ---------------------------------------------------------------------------
__global__ __launch_bounds__(256) void ln_transpose(
    const float* __restrict__ x,            // (B, C, N) f32
    const float* __restrict__ g,            // (C,) f32
    unsigned short* __restrict__ xnt) {     // (B, N, C) bf16
  __shared__ __align__(16) float slab[C_ * 64];            // [c][n], 128 KB
  __shared__ __align__(16) unsigned short tile2[64 * 65];  // [c-chunk][n] bf16
  __shared__ float red[256], red2[256];
  __shared__ float meanS[64], rstdS[64];

  const int b = blockIdx.y, n0 = blockIdx.x * 64;
  const int t = threadIdx.x;
  const float* xb = x + (size_t)b * C_ * N_ + n0;

  // phase 1: DMA the slab (16 lanes per c-row, 4 f32/lane)
#pragma unroll
  for (int call = 0; call < 32; ++call) {
    int c = call * 16 + (t >> 4);
    async_copy16(&xb[(size_t)c * N_ + (t & 15) * 4], &slab[call * 1024 + t * 4]);
  }
  asm volatile("s_waitcnt vmcnt(0)" ::: "memory");
  __syncthreads();

  // phase 2: stats — 4 c-partials per n (lanes vary n: 2-way, free)
  {
    const int n = t & 63, cb = (t >> 6) * 128;
    float s = 0.f, s2 = 0.f;
    for (int c = cb; c < cb + 128; ++c) {
      float v = slab[c * 64 + n];
      s += v; s2 += v * v;
    }
    red[t] = s; red2[t] = s2;
  }
  __syncthreads();
  if (t < 64) {
    float ts  = red[t]  + red[t + 64]  + red[t + 128]  + red[t + 192];
    float ts2 = red2[t] + red2[t + 64] + red2[t + 128] + red2[t + 192];
    float mean = ts * (1.0f / C_);
    float var  = ts2 * (1.0f / C_) - mean * mean;
    meanS[t] = mean;
    rstdS[t] = rsqrtf(var + 1e-5f);
  }
  __syncthreads();

  unsigned short* xout = xnt + ((size_t)b * N_ + n0) * C_;
  for (int c0 = 0; c0 < C_; c0 += 64) {
    // normalize into padded tile (lanes vary n: conflict-free)
    for (int e = t; e < 64 * 64; e += 256) {
      int cl = e >> 6, nl = e & 63;
      float v = slab[(c0 + cl) * 64 + nl];
      tile2[cl * 65 + nl] = f2bf((v - meanS[nl]) * rstdS[nl] * g[c0 + cl]);
    }
    __syncthreads();
    // transposed write: 4 c per lane, consecutive lanes -> consecutive c
    for (int e = t; e < 64 * 16; e += 256) {
      int nl = e >> 4, c4 = (e & 15) * 4;
      short4v pk;
#pragma unroll
      for (int j = 0; j < 4; ++j) pk[j] = (short)tile2[(c4 + j) * 65 + nl];
      *(short4v*)&xout[(size_t)nl * C_ + c0 + c4] = pk;
    }
    __syncthreads();
  }
}

// ---------------------------------------------------------------------------
// Kernel 2: QKV GEMM (bf16, 128x128 tile, BK=64, K-chunk XOR swizzle).
// Epilogue: q -> (b,h,n,d)*0.125, k -> (b,h,n,d), v -> (b,h,d,n).
// ---------------------------------------------------------------------------
__global__ __launch_bounds__(256) void qkv_gemm(
    const unsigned short* __restrict__ W,    // (1536, 512) bf16
    const unsigned short* __restrict__ xnt,  // (B, N, C) bf16
    unsigned short* __restrict__ qt,
    unsigned short* __restrict__ kt,
    unsigned short* __restrict__ vt) {
  __shared__ __align__(16) short As[128 * 64];
  __shared__ __align__(16) short Bs[128 * 64];

  const int n0 = blockIdx.x * 128, m0 = blockIdx.y * 128, b = blockIdx.z;
  const int t = threadIdx.x;
  const int lane = t & 63, wave = t >> 6;
  const int col = lane & 15, quad = lane >> 4;
  const int wRow = (wave >> 1) * 64, wCol = (wave & 1) * 64;
  const unsigned short* xb = xnt + (size_t)b * N_ * C_;
  const int ldr = t >> 3;
  const int ldc8 = (((t & 7) ^ (ldr & 7)) * 8);
  const int cs = col & 7;

  f32x4 acc[4][4] = {};

  for (int k0 = 0; k0 < C_; k0 += 64) {
    __syncthreads();
#pragma unroll
    for (int call = 0; call < 4; ++call) {
      async_copy16(&W[(size_t)(m0 + call * 32 + ldr) * C_ + k0 + ldc8],
                   &As[call * 2048 + t * 8]);
      async_copy16(&xb[(size_t)(n0 + call * 32 + ldr) * C_ + k0 + ldc8],
                   &Bs[call * 2048 + t * 8]);
    }
    asm volatile("s_waitcnt vmcnt(0)" ::: "memory");
    __syncthreads();
#pragma unroll
    for (int ks = 0; ks < 2; ++ks) {
      bf16x8 a[4], bb[4];
      const int kc = ((ks * 4 + quad) ^ cs) * 8;
#pragma unroll
      for (int i = 0; i < 4; ++i)
        a[i] = *(const bf16x8*)&As[(wRow + i * 16 + col) * 64 + kc];
#pragma unroll
      for (int j = 0; j < 4; ++j)
        bb[j] = *(const bf16x8*)&Bs[(wCol + j * 16 + col) * 64 + kc];
#pragma unroll
      for (int i = 0; i < 4; ++i)
#pragma unroll
        for (int j = 0; j < 4; ++j)
          acc[i][j] = __builtin_amdgcn_mfma_f32_16x16x32_bf16(a[i], bb[j], acc[i][j], 0, 0, 0);
    }
  }

  const int sect = m0 >> 9;
  const int mloc = (m0 & 511) + wRow;
  const int h = mloc >> 6;
  if (sect < 2) {
    unsigned short* dst = (sect == 0 ? qt : kt) + ((size_t)b * H_ + h) * N_ * D_;
    const float scl = (sect == 0) ? 0.125f : 1.0f;
#pragma unroll
    for (int i = 0; i < 4; ++i) {
      int d0 = i * 16 + quad * 4;
#pragma unroll
      for (int j = 0; j < 4; ++j) {
        int n = n0 + wCol + j * 16 + col;
        short4v pk;
#pragma unroll
        for (int r = 0; r < 4; ++r) pk[r] = (short)f2bf(acc[i][j][r] * scl);
        *(short4v*)&dst[(size_t)n * D_ + d0] = pk;
      }
    }
  } else {
    unsigned short* dst = vt + ((size_t)b * H_ + h) * D_ * N_;
#pragma unroll
    for (int i = 0; i < 4; ++i) {
      int d0 = i * 16 + quad * 4;
#pragma unroll
      for (int j = 0; j < 4; ++j) {
        int n = n0 + wCol + j * 16 + col;
#pragma unroll
        for (int r = 0; r < 4; ++r)
          dst[(size_t)(d0 + r) * N_ + n] = f2bf(acc[i][j][r]);
      }
    }
  }
}

// ---------------------------------------------------------------------------
// Kernel 3: flash attention. BQ=256, 4 waves x 64 Q-rows. No-max softmax via
// __expf. P round-trips through wave-private LDS in 32-col quarters.
// Quarters are software-pipelined: exp/store(qh) -> S-MFMA(qh+1) -> PV(qh),
// so next-quarter QK^T MFMAs fill the DS write->read gap of the P roundtrip.
// __launch_bounds__(256,2): (256,3)'s ~170-VGPR cap spilled accumulators
// (R8: 640 MB scratch). grid (8,64) = 2 blocks/CU (grid-limited).
// ---------------------------------------------------------------------------
#define PSTR4 40  // P quarter-buffer row stride (shorts)

__global__ __launch_bounds__(256, 2) void attn(
    const unsigned short* __restrict__ qt,   // (B,H,N,D), pre-scaled
    const unsigned short* __restrict__ kt,   // (B,H,N,D)
    const unsigned short* __restrict__ vt,   // (B,H,D,N)
    unsigned short* __restrict__ aot) {      // (B,N,HID)
  __shared__ __align__(16) short Ks[128 * 64];        // (j,d) swizzled; Q rows 0-127 at start
  __shared__ __align__(16) short Vs[64 * 128];        // (d,j) swizzled; Q rows 128-255 at start
  __shared__ __align__(16) short Ps[4 * 64 * PSTR4];  // per-wave P quarter (64 rows x 32 cols)

  const int q0 = blockIdx.x * 256;
  const int bh = blockIdx.y;
  const int t = threadIdx.x, lane = t & 63, wave = t >> 6;
  const int col = lane & 15, quad = lane >> 4;
  const int cs = col & 7;
  const unsigned short* qp = qt + (size_t)bh * N_ * D_;
  const unsigned short* kp = kt + (size_t)bh * N_ * D_;
  const unsigned short* vp = vt + (size_t)bh * D_ * N_;
  const int ldr = t >> 3;
  const int ldc8 = (((t & 7) ^ (ldr & 7)) * 8);
  const int vdr = t >> 4;
  const int vdc8 = (((t & 15) ^ (vdr & 7)) * 8);

  // stage Q tile (256x64, swizzled) into Ks+Vs, pull A-fragments to registers
#pragma unroll
  for (int call = 0; call < 4; ++call)
    async_copy16(&qp[(size_t)(q0 + call * 32 + ldr) * D_ + ldc8], &Ks[call * 2048 + t * 8]);
#pragma unroll
  for (int call = 0; call < 4; ++call)
    async_copy16(&qp[(size_t)(q0 + 128 + call * 32 + ldr) * D_ + ldc8], &Vs[call * 2048 + t * 8]);
  asm volatile("s_waitcnt vmcnt(0)" ::: "memory");
  __syncthreads();
  const short* Qsrc = (wave < 2) ? Ks : Vs;
  const int qr0 = (wave & 1) * 64;
  bf16x8 qf[4][2];
#pragma unroll
  for (int i = 0; i < 4; ++i)
#pragma unroll
    for (int ks = 0; ks < 2; ++ks)
      qf[i][ks] = *(const bf16x8*)&Qsrc[(qr0 + i * 16 + col) * 64 + ((ks * 4 + quad) ^ cs) * 8];
  __syncthreads();

  bf16x8 onesb;
#pragma unroll
  for (int j = 0; j < 8; ++j) onesb[j] = (short)0x3F80;  // bf16 1.0

  f32x4 O[4][4] = {};
  f32x4 L[4] = {};
  short* Pw = &Ps[wave * 64 * PSTR4];

  auto compute_S = [&](int qh, f32x4 (&Sd)[4][2]) {
#pragma unroll
    for (int i = 0; i < 4; ++i)
#pragma unroll
      for (int jtl = 0; jtl < 2; ++jtl)
        Sd[i][jtl] = (f32x4){0.f, 0.f, 0.f, 0.f};
#pragma unroll
    for (int ks = 0; ks < 2; ++ks) {
      const int kc = ((ks * 4 + quad) ^ cs) * 8;
#pragma unroll
      for (int jtl = 0; jtl < 2; ++jtl) {
        bf16x8 kb = *(const bf16x8*)&Ks[((qh * 2 + jtl) * 16 + col) * 64 + kc];
#pragma unroll
        for (int i = 0; i < 4; ++i)
          Sd[i][jtl] = __builtin_amdgcn_mfma_f32_16x16x32_bf16(qf[i][ks], kb, Sd[i][jtl], 0, 0, 0);
      }
    }
  };

  for (int j0 = 0; j0 < N_; j0 += 128) {
    __syncthreads();
#pragma unroll
    for (int call = 0; call < 4; ++call)
      async_copy16(&kp[(size_t)(j0 + call * 32 + ldr) * D_ + ldc8], &Ks[call * 2048 + t * 8]);
#pragma unroll
    for (int call = 0; call < 4; ++call)
      async_copy16(&vp[(size_t)(call * 16 + vdr) * N_ + j0 + vdc8], &Vs[call * 2048 + t * 8]);
    asm volatile("s_waitcnt vmcnt(0)" ::: "memory");
    __syncthreads();

    f32x4 Sbuf[2][4][2];
    compute_S(0, Sbuf[0]);
#pragma unroll
    for (int qh = 0; qh < 4; ++qh) {
      f32x4 (&Sc)[4][2] = Sbuf[qh & 1];
      // P = exp(S); round to bf16, store to wave-private LDS
#pragma unroll
      for (int i = 0; i < 4; ++i)
#pragma unroll
        for (int jtl = 0; jtl < 2; ++jtl)
#pragma unroll
          for (int r = 0; r < 4; ++r) {
            float p = __expf(Sc[i][jtl][r]);
            unsigned u;
            __builtin_memcpy(&u, &p, 4);
            Pw[(i * 16 + quad * 4 + r) * PSTR4 + jtl * 16 + col] =
                (unsigned short)((u + 0x8000u) >> 16);
          }
      // next quarter's QK^T fills the DS write->read gap
      if (qh < 3) compute_S(qh + 1, Sbuf[(qh + 1) & 1]);
      // PV on this quarter (DS ops in-order per wave: no barrier needed)
      bf16x8 pa[4], vb[4];
#pragma unroll
      for (int i = 0; i < 4; ++i)
        pa[i] = *(const bf16x8*)&Pw[(i * 16 + col) * PSTR4 + quad * 8];
      const int vc = ((qh * 4 + quad) ^ cs) * 8;
#pragma unroll
      for (int dt = 0; dt < 4; ++dt)
        vb[dt] = *(const bf16x8*)&Vs[(dt * 16 + col) * 128 + vc];
#pragma unroll
      for (int i = 0; i < 4; ++i) {
#pragma unroll
        for (int dt = 0; dt < 4; ++dt)
          O[i][dt] = __builtin_amdgcn_mfma_f32_16x16x32_bf16(pa[i], vb[dt], O[i][dt], 0, 0, 0);
        L[i] = __builtin_amdgcn_mfma_f32_16x16x32_bf16(pa[i], onesb, L[i], 0, 0, 0);
      }
    }
  }

  // epilogue: normalize by l, write ao_t[b][n][h*64+d]
  const int b = bh >> 3, h = bh & 7;
  unsigned short* ob = aot + (size_t)b * N_ * HID_;
#pragma unroll
  for (int i = 0; i < 4; ++i) {
#pragma unroll
    for (int r = 0; r < 4; ++r) {
      int n = q0 + wave * 64 + i * 16 + quad * 4 + r;
      float inv = 1.0f / L[i][r];
#pragma unroll
      for (int dt = 0; dt < 4; ++dt)
        ob[(size_t)n * HID_ + h * 64 + dt * 16 + col] = f2bf(O[i][dt][r] * inv);
    }
  }
}

// ---------------------------------------------------------------------------
// Kernel 4: out GEMM (bf16 MFMA, f32 bias, f32 output), K-chunk XOR swizzle.
// ---------------------------------------------------------------------------
__global__ __launch_bounds__(256) void out_gemm(
    const unsigned short* __restrict__ W,    // (512, 512) bf16
    const unsigned short* __restrict__ aot,  // (B, N, HID) bf16
    const float* __restrict__ bias,          // (512,) f32
    float* __restrict__ out) {               // (B, C, N) f32
  __shared__ __align__(16) short As[128 * 64];
  __shared__ __align__(16) short Bs[128 * 64];

  const int n0 = blockIdx.x * 128, m0 = blockIdx.y * 128, b = blockIdx.z;
  const int t = threadIdx.x;
  const int lane = t & 63, wave = t >> 6;
  const int col = lane & 15, quad = lane >> 4;
  const int wRow = (wave >> 1) * 64, wCol = (wave & 1) * 64;
  const unsigned short* xb = aot + (size_t)b * N_ * HID_;
  const int ldr = t >> 3;
  const int ldc8 = (((t & 7) ^ (ldr & 7)) * 8);
  const int cs = col & 7;

  f32x4 acc[4][4] = {};

  for (int k0 = 0; k0 < HID_; k0 += 64) {
    __syncthreads();
#pragma unroll
    for (int call = 0; call < 4; ++call) {
      async_copy16(&W[(size_t)(m0 + call * 32 + ldr) * HID_ + k0 + ldc8],
                   &As[call * 2048 + t * 8]);
      async_copy16(&xb[(size_t)(n0 + call * 32 + ldr) * HID_ + k0 + ldc8],
                   &Bs[call * 2048 + t * 8]);
    }
    asm volatile("s_waitcnt vmcnt(0)" ::: "memory");
    __syncthreads();
#pragma unroll
    for (int ks = 0; ks < 2; ++ks) {
      bf16x8 a[4], bb[4];
      const int kc = ((ks * 4 + quad) ^ cs) * 8;
#pragma unroll
      for (int i = 0; i < 4; ++i)
        a[i] = *(const bf16x8*)&As[(wRow + i * 16 + col) * 64 + kc];
#pragma unroll
      for (int j = 0; j < 4; ++j)
        bb[j] = *(const bf16x8*)&Bs[(wCol + j * 16 + col) * 64 + kc];
#pragma unroll
      for (int i = 0; i < 4; ++i)
#pragma unroll
        for (int j = 0; j < 4; ++j)
          acc[i][j] = __builtin_amdgcn_mfma_f32_16x16x32_bf16(a[i], bb[j], acc[i][j], 0, 0, 0);
    }
  }

#pragma unroll
  for (int i = 0; i < 4; ++i) {
#pragma unroll
    for (int r = 0; r < 4; ++r) {
      int m = m0 + wRow + i * 16 + quad * 4 + r;
      float bv = bias[m];
#pragma unroll
      for (int j = 0; j < 4; ++j) {
        int n = n0 + wCol + j * 16 + col;
        out[((size_t)b * C_ + m) * N_ + n] = acc[i][j][r] + bv;
      }
    }
  }
}

extern "C" void kernel_launch(void* const* d_in, const int* in_sizes, int n_in,
                              void* d_out, int out_size, void* d_ws, size_t ws_size,
                              hipStream_t stream) {
  const float* x    = (const float*)d_in[0];
  const float* g    = (const float*)d_in[1];
  const float* Wqkv = (const float*)d_in[2];
  const float* Wout = (const float*)d_in[3];
  const float* bout = (const float*)d_in[4];
  float* out = (float*)d_out;

  unsigned short* ws  = (unsigned short*)d_ws;
  unsigned short* xnt = ws;                                  // B*N*C
  unsigned short* qt  = xnt + (size_t)B_ * N_ * C_;
  unsigned short* kt  = qt  + (size_t)B_ * H_ * N_ * D_;
  unsigned short* vt  = kt  + (size_t)B_ * H_ * N_ * D_;
  unsigned short* aot = vt  + (size_t)B_ * H_ * D_ * N_;     // B*N*HID
  unsigned short* Wqb = aot + (size_t)B_ * N_ * HID_;        // 1536*512
  unsigned short* Wob = Wqb + (size_t)3 * HID_ * C_;         // 512*512

  wcvt2<<<dim3(256), 256, 0, stream>>>(Wqkv, Wqb, 3 * HID_ * C_ / 4,
                                       Wout, Wob, C_ * HID_ / 4);
  ln_transpose<<<dim3(N_ / 64, B_), 256, 0, stream>>>(x, g, xnt);
  qkv_gemm<<<dim3(N_ / 128, 12, B_), 256, 0, stream>>>(Wqb, xnt, qt, kt, vt);
  attn<<<dim3(N_ / 256, B_ * H_), 256, 0, stream>>>(qt, kt, vt, aot);
  out_gemm<<<dim3(N_ / 128, 4, B_), 256, 0, stream>>>(Wob, aot, bout, out);
}